// Round 2
// baseline (124.552 us; speedup 1.0000x reference)
//
#include <hip/hip_runtime.h>

// Bilateral filter, fixed shape: x[16,3,512,512] fp32, K=5, pad=2 reflect.
// sigma_color = sigma_space = 1.1; normalizations cancel in the ratio.
// w = exp2(coef2*d^2 + coef2*sij), coef2 = -log2(e)/2.42.
//
// R5 restructure (resubmitted R6 — prior bench was an infra timeout, never
// ran): one thread = 4x2 pixel tile; window held as OVERLAPPING v2f PAIRS
// P[6][7], P[k][j] = (win[k][j], win[k][j+1]), built once and pinned.
// Inner loop reads pA=P[r][dj], pB=P[r][dj+2], cA=P[c][2], cB=P[c][4] as
// direct aligned VGPR-pair operands for v_pk_* — zero per-iteration v_mov
// (the 4x4 version forced the compiler to re-pack scalar regs into pairs
// every tap). Center tap (d=0,s=0 -> w=1 exact) folded into accumulator
// init: 24 taps x (10 pk + 4 exp) per oi.
// Tile is 4x2 (not 4x4) so the pair file fits 128 VGPRs at 4 waves/EU:
// 42 pairs (84) + 4 v2f accum (8) + temps ~12 ~= 110.
//
// Column reflect (verified R2-R4 logic, reused):
//   w0==0  : col -2 -> c4.z (col 2), col -1 -> l2.y (col 1)
//   w0==508: col 512 -> r2.x (col 510), col 513 -> c4.y (col 509)
// Row reflect: r = min(abs(r), 2*(H-1)-r).

typedef float v2f __attribute__((ext_vector_type(2)));

constexpr int H_ = 512;
constexpr int W_ = 512;

__global__ __launch_bounds__(256, 4) void bilateral_kernel(
    const float* __restrict__ x,
    float* __restrict__ out,
    int nthreads)
{
    int t = blockIdx.x * 256 + threadIdx.x;
    if (t >= nthreads) return;

    int qx = t & 127;          // tile col index (4-wide tiles)
    int rg = (t >> 7) & 255;   // tile row index (2-tall tiles)
    int pl = t >> 15;          // plane (b*C + c)
    int w0 = qx << 2;
    int h0 = rg << 1;
    const float* plane = x + ((long)pl << 18);   // 512*512
    float* oplane = out + ((long)pl << 18);

    int aL = max(w0 - 2, 0);
    int aR = min(w0 + 4, W_ - 2);
    bool bL = (w0 == 0);
    bool bR = (w0 == W_ - 4);

    // P[k][j] = (win[k][j], win[k][j+1]), rows h0-2 .. h0+3, cols w0-2 .. w0+5.
    v2f P[6][7];
#pragma unroll
    for (int k = 0; k < 6; ++k) {
        int r = h0 + k - 2;
        r = min(abs(r), 2 * (H_ - 1) - r);
        const float* rp = plane + r * W_;
        float2 l2 = *(const float2*)(rp + aL);
        float4 c4 = *(const float4*)(rp + w0);
        float2 r2 = *(const float2*)(rp + aR);
        float e0 = bL ? c4.z : l2.x;   // reflect col -2 -> +2
        float e1 = l2.y;               // col -1 (== col 1 when bL)
        float e6 = r2.x;               // col +4 (== col 510 when bR)
        float e7 = bR ? c4.y : r2.y;   // reflect col 513 -> 509
        P[k][0] = (v2f){e0,   e1};
        P[k][1] = (v2f){e1,   c4.x};
        P[k][2] = (v2f){c4.x, c4.y};
        P[k][3] = (v2f){c4.y, c4.z};
        P[k][4] = (v2f){c4.z, c4.w};
        P[k][5] = (v2f){c4.w, e6};
        P[k][6] = (v2f){e6,   e7};
    }

    // Pin the pair file: forces all 42 pairs live in aligned VGPR pairs here,
    // defeating the min-VGPR rolling-repack the compiler otherwise does.
#pragma unroll
    for (int k = 0; k < 6; ++k)
#pragma unroll
        for (int j = 0; j < 7; ++j)
            asm volatile("" : "+v"(P[k][j]));

    const float coef2 = -0.59615498f;  // -log2(e)/(2*1.21)
    const v2f k2 = {coef2, coef2};

#pragma unroll
    for (int oi = 0; oi < 2; ++oi) {
        v2f cA = P[oi + 2][2];   // centers: pixels (w0, w0+1)
        v2f cB = P[oi + 2][4];   // centers: pixels (w0+2, w0+3)
        // Center tap folded in exactly: d=0, s=0 -> w = exp2(-0.0) = 1.0.
        v2f numA = cA, denA = {1.f, 1.f};
        v2f numB = cB, denB = {1.f, 1.f};
#pragma unroll
        for (int di = 0; di < 5; ++di) {
#pragma unroll
            for (int dj = 0; dj < 5; ++dj) {
                if (di == 2 && dj == 2) continue;   // center handled above
                float csf = coef2 * (float)((di - 2) * (di - 2) +
                                            (dj - 2) * (dj - 2));
                v2f cs = {csf, csf};
                v2f pA = P[oi + di][dj];       // direct pair operand
                v2f pB = P[oi + di][dj + 2];   // pB(dj) == pA(dj+2)
                v2f dA = pA - cA;
                v2f dB = pB - cB;
                v2f argA = (dA * k2) * dA + cs;   // pk_mul + pk_fma
                v2f argB = (dB * k2) * dB + cs;
                v2f wA, wB;
                wA.x = __builtin_amdgcn_exp2f(argA.x);
                wA.y = __builtin_amdgcn_exp2f(argA.y);
                wB.x = __builtin_amdgcn_exp2f(argB.x);
                wB.y = __builtin_amdgcn_exp2f(argB.y);
                numA += wA * pA;   // pk_fma
                denA += wA;        // pk_add
                numB += wB * pB;
                denB += wB;
            }
        }
        float4 o;
        o.x = numA.x * __builtin_amdgcn_rcpf(denA.x);
        o.y = numA.y * __builtin_amdgcn_rcpf(denA.y);
        o.z = numB.x * __builtin_amdgcn_rcpf(denB.x);
        o.w = numB.y * __builtin_amdgcn_rcpf(denB.y);
        *(float4*)(oplane + (h0 + oi) * W_ + w0) = o;
    }
}

extern "C" void kernel_launch(void* const* d_in, const int* in_sizes, int n_in,
                              void* d_out, int out_size, void* d_ws, size_t ws_size,
                              hipStream_t stream)
{
    const float* x = (const float*)d_in[0];
    float* out = (float*)d_out;
    int nthreads = in_sizes[0] >> 3;         // 8 px per thread (4x2 tile)
    int blocks = (nthreads + 255) / 256;
    bilateral_kernel<<<blocks, 256, 0, stream>>>(x, out, nthreads);
}